// Round 8
// baseline (326.384 us; speedup 1.0000x reference)
//
#include <hip/hip_runtime.h>
#include <math.h>

#define NB       1025
#define FFTN     2048
#define HOP      512
#define NFRAMES  4000
#define BATCH    4
#define OUT_T    2047488          // (F-1)*hop + N - 2*half
#define R_HOPS   8
#define REG_PB   501              // ceil(4003/8)
#define ACC_N    (R_HOPS * HOP)   // 4096 floats = 16 KB
#define PI_F     3.14159265358979323846f

__device__ __forceinline__ float2 cmul(float2 a, float2 b) {
    return make_float2(fmaf(a.x, b.x, -a.y*b.y), fmaf(a.x, b.y, a.y*b.x));
}
__device__ __forceinline__ float2 cadd(float2 a, float2 b){ return make_float2(a.x+b.x, a.y+b.y); }
__device__ __forceinline__ float2 csub(float2 a, float2 b){ return make_float2(a.x-b.x, a.y-b.y); }
__device__ __forceinline__ float2 caddi(float2 a, float2 b){ return make_float2(a.x-b.y, a.y+b.x); } // a + i*b
__device__ __forceinline__ float2 csubi(float2 a, float2 b){ return make_float2(a.x+b.y, a.y-b.x); } // a - i*b

template<int CTRL>
__device__ __forceinline__ float dppx(float v) {
    return __int_as_float(__builtin_amdgcn_mov_dpp(__float_as_int(v), CTRL, 0xF, 0xF, true));
}

// window_sumsquare at trimmed position p (boundary path, <=4 terms)
__device__ __forceinline__ float wsq_at(int p) {
    int u  = p + FFTN / 2;
    int fm = u >> 9;
    int n0 = u & 511;
    float wsq = 0.f;
    #pragma unroll
    for (int jj = 0; jj < 4; ++jj) {
        int fr = fm - jj;
        if (fr >= 0 && fr < NFRAMES) {
            int n = n0 + (jj << 9);
            float sw = __sinf((PI_F / (float)FFTN) * (float)n);
            float w  = sw * sw;
            wsq += w * w;
        }
    }
    const float tiny = 1.17549435e-38f;
    return (wsq > tiny) ? wsq : 1.0f;
}

// 16-pt inverse DFT, fully in registers: r[out_idx] = sum_e w16^{out_idx*e} r[e]
__device__ __forceinline__ void ifft16(float2 (&r)[16]) {
    const float C1 = 0.923879532511286756f, S1 = 0.382683432365089772f;
    const float C2 = 0.707106781186547524f;
    float2 P[16];
    float2 t0, t1, t2, t3;
    #pragma unroll
    for (int e1 = 0; e1 < 4; ++e1) {
        float2 x0 = r[e1], x1 = r[e1+4], x2 = r[e1+8], x3 = r[e1+12];
        t0 = cadd(x0, x2); t1 = csub(x0, x2);
        t2 = cadd(x1, x3); t3 = csub(x1, x3);
        P[e1*4+0] = cadd(t0, t2);
        P[e1*4+1] = caddi(t1, t3);
        P[e1*4+2] = csub(t0, t2);
        P[e1*4+3] = csubi(t1, t3);
    }
    // twiddles w16^{a*e1}
    P[1*4+1] = cmul(P[1*4+1], make_float2( C1,  S1));
    P[1*4+2] = cmul(P[1*4+2], make_float2( C2,  C2));
    P[1*4+3] = cmul(P[1*4+3], make_float2( S1,  C1));
    P[2*4+1] = cmul(P[2*4+1], make_float2( C2,  C2));
    P[2*4+2] = make_float2(-P[2*4+2].y, P[2*4+2].x);          // * i
    P[2*4+3] = cmul(P[2*4+3], make_float2(-C2,  C2));
    P[3*4+1] = cmul(P[3*4+1], make_float2( S1,  C1));
    P[3*4+2] = cmul(P[3*4+2], make_float2(-C2,  C2));
    P[3*4+3] = cmul(P[3*4+3], make_float2(-C1, -S1));
    #pragma unroll
    for (int a = 0; a < 4; ++a) {
        float2 x0 = P[0*4+a], x1 = P[1*4+a], x2 = P[2*4+a], x3 = P[3*4+a];
        t0 = cadd(x0, x2); t1 = csub(x0, x2);
        t2 = cadd(x1, x3); t3 = csub(x1, x3);
        r[a+0 ] = cadd(t0, t2);
        r[a+4 ] = caddi(t1, t3);
        r[a+8 ] = csub(t0, t2);
        r[a+12] = csubi(t1, t3);
    }
}

// Wave-autonomous four-step ISTFT: one wave = one frame's 1024-pt IFFT.
// 1024 = 16(regs) x [16(regs) x 4(DPP quad)]; single wave-private LDS
// transpose; no block barriers in the main loop; LDS-atomic OLA.
__global__ __launch_bounds__(256, 3) void istft_wave2_kernel(
    const float* __restrict__ sr, const float* __restrict__ si,
    float* __restrict__ out)
{
    __shared__ float2 tbuf[4][1024];   // 32 KB: per-wave transpose buffer
    __shared__ float  acc[ACC_N];      // 16 KB: region accumulator

    const int tid  = threadIdx.x;
    const int w    = tid >> 6;
    const int t    = tid & 63;         // lane
    const int n2   = t >> 2;
    const int u    = t & 3;
    const int br2u = ((u & 1) << 1) | (u >> 1);   // bit-reverse2(u)
    const int blk  = blockIdx.x;
    const int b    = blk / REG_PB;
    const int reg  = blk - b * REG_PB;
    const int s0h  = reg * R_HOPS;

    float2* tb = tbuf[w];

    #pragma unroll
    for (int q = 0; q < ACC_N / 256; ++q) acc[tid + q * 256] = 0.f;

    // ---- per-lane constants ----
    float2 bt, wt, wu;
    {
        float sv, cv;
        __sincosf((PI_F / 1024.f) * (float)t, &sv, &cv);
        bt = make_float2(cv, sv);          // e^{i pi t/1024}
        wt = cmul(bt, bt);                 // w1024^t
        __sincosf((PI_F / 32.f) * (float)u, &sv, &cv);
        wu = make_float2(cv, sv);          // w64^u
    }
    // window: w32[h][m] = sin^2(pi*(2n2+512*br2u+32m+h)/2048) / 1024
    float w32[2][16];
    #pragma unroll
    for (int m = 0; m < 16; ++m) {
        #pragma unroll
        for (int h = 0; h < 2; ++h) {
            int to = 2 * n2 + 512 * br2u + 32 * m + h;
            float sv = __sinf((PI_F / 2048.f) * (float)to);
            w32[h][m] = sv * sv * (1.f / 1024.f);
        }
    }

    int f0 = s0h - 3;           if (f0 < 0)           f0 = 0;
    int f1 = s0h + R_HOPS - 1;  if (f1 > NFRAMES - 1) f1 = NFRAMES - 1;

    __syncthreads();   // acc zeroed

    const float2 E16 = make_float2(0.980785280403230449f, 0.195090322016128268f); // e^{i pi/16}
    const float sXc = (u & 2) ? -1.f : 1.f;
    const float sYc = (u & 1) ? -1.f : 1.f;

    for (int f = f0 + w; f <= f1; f += 4) {
        const size_t fb = ((size_t)b * NFRAMES + f) * NB;
        const float* __restrict__ xr = sr + fb;
        const float* __restrict__ xi = si + fb;

        // ---- load + Hermitian pack: z[e] = Z[t + 64e] ----
        float2 z[16];
        float2 te = bt;                       // e^{i pi (t+64e)/1024}
        #pragma unroll
        for (int e = 0; e < 16; ++e) {
            int k  = t + 64 * e;
            int mk = 1024 - k;
            float arv = xr[k],  aiv = xi[k];
            float brv = xr[mk], biv = xi[mk];
            if (e == 0) { if (t == 0) { aiv = 0.f; biv = 0.f; } }  // DC/Nyquist imag ignored
            float Er = 0.5f * (arv + brv), Ei = 0.5f * (aiv - biv);
            float Dr = 0.5f * (arv - brv), Di = 0.5f * (aiv + biv);
            float Or = fmaf(Dr, te.x, -Di * te.y);
            float Oi = fmaf(Dr, te.y,  Di * te.x);
            z[e] = make_float2(Er - Oi, Ei + Or);
            if (e < 15) te = cmul(te, E16);
        }

        // ---- step A: 16-pt IFFT over e (result indexed by q = n2-digit) ----
        ifft16(z);
        // ---- twiddle w1024^{q*t} (chained) ----
        {
            float2 tw = wt;
            #pragma unroll
            for (int q = 1; q < 16; ++q) {
                z[q] = cmul(z[q], tw);
                if (q < 15) tw = cmul(tw, wt);
            }
        }

        // ---- LDS transpose (wave-private, no barrier): addr(t,q)=16t+(q^(t&14)) ----
        #pragma unroll
        for (int mm = 0; mm < 8; ++mm) {
            int p = 16 * t + ((2 * mm) ^ (t & 14));
            *(float4*)&tb[p] = make_float4(z[2*mm].x, z[2*mm].y, z[2*mm+1].x, z[2*mm+1].y);
        }
        float2 cr[16];
        #pragma unroll
        for (int v = 0; v < 16; ++v) {
            int s = u + 4 * v;
            cr[v] = tb[16 * s + (n2 ^ (s & 14))];
        }

        // ---- step B1: 16-pt IFFT over v (-> index m); pre-twiddle w64^{m u} ----
        ifft16(cr);
        {
            float2 tw = wu;
            #pragma unroll
            for (int m = 1; m < 16; ++m) {
                cr[m] = cmul(cr[m], tw);
                if (m < 15) tw = cmul(tw, wu);
            }
        }

        // ---- step B2: radix-4 across quad lanes (DPP) + window + OLA ----
        // lane (n2,u) ends with g[n2 + 16m + 256*br2u]; x[2n]=Re, x[2n+1]=Im
        const int pb0 = (f - s0h) * 512 + 2 * n2 + 512 * br2u;
        #pragma unroll
        for (int m = 0; m < 16; ++m) {
            float2 U = cr[m];
            float2 p  = make_float2(dppx<0x4E>(U.x), dppx<0x4E>(U.y));   // partner u^2
            float2 B  = make_float2(fmaf(sXc, U.x, p.x), fmaf(sXc, U.y, p.y));
            float2 q2 = make_float2(dppx<0xB1>(B.x), dppx<0xB1>(B.y));   // partner u^1
            float2 m1  = (u & 1) ? q2 : B;
            float2 m2  = (u & 1) ? B  : q2;
            float2 m2r = (u & 2) ? make_float2(-m2.y, m2.x) : m2;        // * i
            float Sx = fmaf(sYc, m2r.x, m1.x);
            float Sy = fmaf(sYc, m2r.y, m1.y);
            int pos = pb0 + 32 * m;
            if ((unsigned)pos < (unsigned)ACC_N) {
                atomicAdd(&acc[pos],     Sx * w32[0][m]);
                atomicAdd(&acc[pos + 1], Sy * w32[1][m]);
            }
        }
    }

    __syncthreads();   // all waves' accumulates done

    // ---- epilogue: divide by window_sumsquare, write once, coalesced ----
    const int base_u = s0h * HOP;
    float* outb = out + (size_t)b * OUT_T;
    #pragma unroll
    for (int q = 0; q < ACC_N / 256; ++q) {
        int i = tid + q * 256;
        int p = base_u + i - FFTN / 2;
        if ((unsigned)p < (unsigned)OUT_T) {
            float invw = (p < 512 || p >= OUT_T - 512) ? (1.0f / wsq_at(p)) : (2.0f / 3.0f);
            outb[p] = acc[i] * invw;
        }
    }
}

extern "C" void kernel_launch(void* const* d_in, const int* in_sizes, int n_in,
                              void* d_out, int out_size, void* d_ws, size_t ws_size,
                              hipStream_t stream) {
    const float* sr = (const float*)d_in[0];
    const float* si = (const float*)d_in[1];
    float* out = (float*)d_out;
    istft_wave2_kernel<<<BATCH * REG_PB, 256, 0, stream>>>(sr, si, out);
}

// Round 9
// 222.590 us; speedup vs baseline: 1.4663x; 1.4663x over previous
//
#include <hip/hip_runtime.h>
#include <math.h>

#define NB       1025
#define FFTN     2048
#define HOP      512
#define NFRAMES  4000
#define BATCH    4
#define OUT_T    2047488          // (F-1)*hop + N - 2*half
#define R_HOPS   8
#define REG_PB   501              // ceil(4003/8)
#define ACC_N    (R_HOPS * HOP)   // 4096 floats = 16 KB
#define PI_F     3.14159265358979323846f

__device__ __forceinline__ float2 cmul(float2 a, float2 b) {
    return make_float2(fmaf(a.x, b.x, -a.y*b.y), fmaf(a.x, b.y, a.y*b.x));
}
__device__ __forceinline__ float2 cadd(float2 a, float2 b){ return make_float2(a.x+b.x, a.y+b.y); }
__device__ __forceinline__ float2 csub(float2 a, float2 b){ return make_float2(a.x-b.x, a.y-b.y); }
__device__ __forceinline__ float2 caddi(float2 a, float2 b){ return make_float2(a.x-b.y, a.y+b.x); } // a + i*b
__device__ __forceinline__ float2 csubi(float2 a, float2 b){ return make_float2(a.x+b.y, a.y-b.x); } // a - i*b

template<int CTRL>
__device__ __forceinline__ float dppx(float v) {
    return __int_as_float(__builtin_amdgcn_mov_dpp(__float_as_int(v), CTRL, 0xF, 0xF, true));
}

// window_sumsquare at trimmed position p (boundary path, <=4 terms)
__device__ __forceinline__ float wsq_at(int p) {
    int u  = p + FFTN / 2;
    int fm = u >> 9;
    int n0 = u & 511;
    float wsq = 0.f;
    #pragma unroll
    for (int jj = 0; jj < 4; ++jj) {
        int fr = fm - jj;
        if (fr >= 0 && fr < NFRAMES) {
            int n = n0 + (jj << 9);
            float sw = __sinf((PI_F / (float)FFTN) * (float)n);
            float w  = sw * sw;
            wsq += w * w;
        }
    }
    const float tiny = 1.17549435e-38f;
    return (wsq > tiny) ? wsq : 1.0f;
}

// 16-pt inverse DFT, fully in registers: r[out_idx] = sum_e w16^{out_idx*e} r[e]
__device__ __forceinline__ void ifft16(float2 (&r)[16]) {
    const float C1 = 0.923879532511286756f, S1 = 0.382683432365089772f;
    const float C2 = 0.707106781186547524f;
    float2 P[16];
    float2 t0, t1, t2, t3;
    #pragma unroll
    for (int e1 = 0; e1 < 4; ++e1) {
        float2 x0 = r[e1], x1 = r[e1+4], x2 = r[e1+8], x3 = r[e1+12];
        t0 = cadd(x0, x2); t1 = csub(x0, x2);
        t2 = cadd(x1, x3); t3 = csub(x1, x3);
        P[e1*4+0] = cadd(t0, t2);
        P[e1*4+1] = caddi(t1, t3);
        P[e1*4+2] = csub(t0, t2);
        P[e1*4+3] = csubi(t1, t3);
    }
    // twiddles w16^{a*e1}
    P[1*4+1] = cmul(P[1*4+1], make_float2( C1,  S1));
    P[1*4+2] = cmul(P[1*4+2], make_float2( C2,  C2));
    P[1*4+3] = cmul(P[1*4+3], make_float2( S1,  C1));
    P[2*4+1] = cmul(P[2*4+1], make_float2( C2,  C2));
    P[2*4+2] = make_float2(-P[2*4+2].y, P[2*4+2].x);          // * i
    P[2*4+3] = cmul(P[2*4+3], make_float2(-C2,  C2));
    P[3*4+1] = cmul(P[3*4+1], make_float2( S1,  C1));
    P[3*4+2] = cmul(P[3*4+2], make_float2(-C2,  C2));
    P[3*4+3] = cmul(P[3*4+3], make_float2(-C1, -S1));
    #pragma unroll
    for (int a = 0; a < 4; ++a) {
        float2 x0 = P[0*4+a], x1 = P[1*4+a], x2 = P[2*4+a], x3 = P[3*4+a];
        t0 = cadd(x0, x2); t1 = csub(x0, x2);
        t2 = cadd(x1, x3); t3 = csub(x1, x3);
        r[a+0 ] = cadd(t0, t2);
        r[a+4 ] = caddi(t1, t3);
        r[a+8 ] = csub(t0, t2);
        r[a+12] = csubi(t1, t3);
    }
}

// Wave-autonomous four-step ISTFT: one wave = one frame's 1024-pt IFFT.
// 1024 = 16(regs) x [16(regs) x 4(DPP quad)]; single wave-private LDS
// transpose; no block barriers in the main loop; bank-despread LDS-atomic OLA.
__global__ __launch_bounds__(256) void istft_wave2_kernel(
    const float* __restrict__ sr, const float* __restrict__ si,
    float* __restrict__ out)
{
    __shared__ float2 tbuf[4][1024];   // 32 KB: per-wave transpose buffer
    __shared__ float  acc[ACC_N];      // 16 KB: region accumulator

    const int tid  = threadIdx.x;
    const int w    = tid >> 6;
    const int t    = tid & 63;         // lane
    const int n2   = t >> 2;
    const int u    = t & 3;
    const int br2u = ((u & 1) << 1) | (u >> 1);   // bit-reverse2(u)
    const int blk  = blockIdx.x;
    const int b    = blk / REG_PB;
    const int reg  = blk - b * REG_PB;
    const int s0h  = reg * R_HOPS;

    float2* tb = tbuf[w];

    #pragma unroll
    for (int q = 0; q < ACC_N / 256; ++q) acc[tid + q * 256] = 0.f;

    // ---- per-lane constants ----
    float2 bt, wt, wu;
    {
        float sv, cv;
        __sincosf((PI_F / 1024.f) * (float)t, &sv, &cv);
        bt = make_float2(cv, sv);          // e^{i pi t/1024}
        wt = cmul(bt, bt);                 // w1024^t
        __sincosf((PI_F / 32.f) * (float)u, &sv, &cv);
        wu = make_float2(cv, sv);          // w64^u
    }

    int f0 = s0h - 3;           if (f0 < 0)           f0 = 0;
    int f1 = s0h + R_HOPS - 1;  if (f1 > NFRAMES - 1) f1 = NFRAMES - 1;

    __syncthreads();   // acc zeroed

    const float2 E16 = make_float2(0.980785280403230449f, 0.195090322016128268f); // e^{i pi/16}
    const float CD = 0.99999882345170188f;     // cos(pi/2048)
    const float SD = 0.00153398018628476550f;  // sin(pi/2048)
    const float sXc = (u & 2) ? -1.f : 1.f;
    const float sYc = (u & 1) ? -1.f : 1.f;
    const int   tl0 = 2 * n2 + 512 * br2u;     // frame-local base position (even)

    for (int f = f0 + w; f <= f1; f += 4) {
        const size_t fb = ((size_t)b * NFRAMES + f) * NB;
        const float* __restrict__ xr = sr + fb;
        const float* __restrict__ xi = si + fb;

        // ---- load + Hermitian pack: z[e] = Z[t + 64e] ----
        float2 z[16];
        float2 te = bt;                       // e^{i pi (t+64e)/1024}
        #pragma unroll
        for (int e = 0; e < 16; ++e) {
            int k  = t + 64 * e;
            int mk = 1024 - k;
            float arv = xr[k],  aiv = xi[k];
            float brv = xr[mk], biv = xi[mk];
            if (e == 0) { if (t == 0) { aiv = 0.f; biv = 0.f; } }  // DC/Nyquist imag ignored
            float Er = 0.5f * (arv + brv), Ei = 0.5f * (aiv - biv);
            float Dr = 0.5f * (arv - brv), Di = 0.5f * (aiv + biv);
            float Or = fmaf(Dr, te.x, -Di * te.y);
            float Oi = fmaf(Dr, te.y,  Di * te.x);
            z[e] = make_float2(Er - Oi, Ei + Or);
            if (e < 15) te = cmul(te, E16);
        }

        // ---- step A: 16-pt IFFT over e (result indexed by q = n2-digit) ----
        ifft16(z);
        // ---- twiddle w1024^{q*t} (chained) ----
        {
            float2 tw = wt;
            #pragma unroll
            for (int q = 1; q < 16; ++q) {
                z[q] = cmul(z[q], tw);
                if (q < 15) tw = cmul(tw, wt);
            }
        }

        // ---- LDS transpose (wave-private, no barrier): addr(t,q)=16t+(q^(t&14)) ----
        #pragma unroll
        for (int mm = 0; mm < 8; ++mm) {
            int p = 16 * t + ((2 * mm) ^ (t & 14));
            *(float4*)&tb[p] = make_float4(z[2*mm].x, z[2*mm].y, z[2*mm+1].x, z[2*mm+1].y);
        }
        float2 cr[16];
        #pragma unroll
        for (int v = 0; v < 16; ++v) {
            int s = u + 4 * v;
            cr[v] = tb[16 * s + (n2 ^ (s & 14))];
        }

        // ---- step B1: 16-pt IFFT over v (-> index m); pre-twiddle w64^{m u} ----
        ifft16(cr);
        {
            float2 tw = wu;
            #pragma unroll
            for (int m = 1; m < 16; ++m) {
                cr[m] = cmul(cr[m], tw);
                if (m < 15) tw = cmul(tw, wu);
            }
        }

        // ---- step B2: radix-4 across quad lanes (DPP) + window + OLA ----
        // lane (n2,u) ends with g[n2 + 16m + 256*br2u]; x[2n]=Re, x[2n+1]=Im
        const int frel512 = (f - s0h) * 512;
        const int bsw = ((f - s0h) + br2u) & 1;   // bit9 of sample pos
        #pragma unroll
        for (int m = 0; m < 16; ++m) {
            float2 U = cr[m];
            float2 p  = make_float2(dppx<0x4E>(U.x), dppx<0x4E>(U.y));   // partner u^2
            float2 B  = make_float2(fmaf(sXc, U.x, p.x), fmaf(sXc, U.y, p.y));
            float2 q2 = make_float2(dppx<0xB1>(B.x), dppx<0xB1>(B.y));   // partner u^1
            float2 m1  = (u & 1) ? q2 : B;
            float2 m2  = (u & 1) ? B  : q2;
            float2 m2r = (u & 2) ? make_float2(-m2.y, m2.x) : m2;        // * i
            float Sx = fmaf(sYc, m2r.x, m1.x);
            float Sy = fmaf(sYc, m2r.y, m1.y);
            int tloc = tl0 + 32 * m;            // frame-local sample (even)
            int pos  = frel512 + tloc;
            if ((unsigned)pos < (unsigned)ACC_N) {
                // window w(t) = sin^2(pi t/2048)/1024 at tloc, tloc+1
                float sa, ca;
                __sincosf((PI_F / 2048.f) * (float)tloc, &sa, &ca);
                float sb = fmaf(sa, CD, ca * SD);   // sin(angle + pi/2048)
                float vx = Sx * sa * sa * (1.f / 1024.f);
                float vy = Sy * sb * sb * (1.f / 1024.f);
                // bank-despread: sample s stored at s ^ bit9(s)
                atomicAdd(&acc[pos + bsw],     vx);
                atomicAdd(&acc[pos + 1 - bsw], vy);
            }
        }
    }

    __syncthreads();   // all waves' accumulates done

    // ---- epilogue: unscramble, divide by window_sumsquare, coalesced write ----
    const int base_u = s0h * HOP;
    float* outb = out + (size_t)b * OUT_T;
    #pragma unroll
    for (int q = 0; q < ACC_N / 256; ++q) {
        int i = tid + q * 256;
        int s = i ^ ((i >> 9) & 1);     // involution: storage index -> sample
        int p = base_u + s - FFTN / 2;
        if ((unsigned)p < (unsigned)OUT_T) {
            float invw = (p < 512 || p >= OUT_T - 512) ? (1.0f / wsq_at(p)) : (2.0f / 3.0f);
            outb[p] = acc[i] * invw;
        }
    }
}

extern "C" void kernel_launch(void* const* d_in, const int* in_sizes, int n_in,
                              void* d_out, int out_size, void* d_ws, size_t ws_size,
                              hipStream_t stream) {
    const float* sr = (const float*)d_in[0];
    const float* si = (const float*)d_in[1];
    float* out = (float*)d_out;
    istft_wave2_kernel<<<BATCH * REG_PB, 256, 0, stream>>>(sr, si, out);
}

// Round 10
// 81.713 us; speedup vs baseline: 3.9943x; 2.7240x over previous
//
#include <hip/hip_runtime.h>
#include <math.h>

#define NB       1025
#define M        1024      // half-length complex FFT size
#define FFTN     2048
#define HOP      512
#define NFRAMES  4000
#define BATCH    4
#define OUT_T    2047488   // (F-1)*hop + N - 2*half
#define R_HOPS   8
#define REG_PB   501       // ceil(4003/8)
#define ACC_N    (R_HOPS * HOP)   // 4096 floats = 16 KB
#define PI_F     3.14159265358979323846f

__device__ __forceinline__ float2 cmul(float2 a, float2 b) {
    return make_float2(a.x*b.x - a.y*b.y, a.x*b.y + a.y*b.x);
}
// float2 bank-pair swizzle — b64 wave64 floor is 4 lanes/bank-pair
__device__ __forceinline__ int SW(int i) { return i ^ ((i >> 4) & 15); }

// window_sumsquare at trimmed position p (boundary path, <=4 terms)
__device__ __forceinline__ float wsq_at(int p) {
    int u  = p + FFTN / 2;
    int fm = u >> 9;
    int n0 = u & 511;
    float wsq = 0.f;
    #pragma unroll
    for (int jj = 0; jj < 4; ++jj) {
        int fr = fm - jj;
        if (fr >= 0 && fr < NFRAMES) {
            int n = n0 + (jj << 9);
            float sw = __sinf((PI_F / (float)FFTN) * (float)n);
            float w  = sw * sw;
            wsq += w * w;
        }
    }
    const float tiny = 1.17549435e-38f;
    return (wsq > tiny) ? wsq : 1.0f;
}

// Out-of-place Stockham stage (reads stride-256, writes digit position).
template<int ST>
__device__ __forceinline__ void stage(const float2* __restrict__ src,
                                      float2* __restrict__ dst, int j,
                                      float2 w1, float2 w2, float2 w3) {
    const int Ns = 1 << (2 * ST);
    float2 v0 = src[SW(j)];
    float2 v1 = src[SW(j + 256)];
    float2 v2 = src[SW(j + 512)];
    float2 v3 = src[SW(j + 768)];
    v1 = cmul(v1, w1); v2 = cmul(v2, w2); v3 = cmul(v3, w3);
    float2 t0 = make_float2(v0.x + v2.x, v0.y + v2.y);
    float2 t1 = make_float2(v0.x - v2.x, v0.y - v2.y);
    float2 t2 = make_float2(v1.x + v3.x, v1.y + v3.y);
    float2 t3 = make_float2(v1.x - v3.x, v1.y - v3.y);
    int jm = j & (Ns - 1);
    int idxD = ((j >> (2 * ST)) << (2 * ST + 2)) + jm;
    dst[SW(idxD         )] = make_float2(t0.x + t2.x, t0.y + t2.y);
    dst[SW(idxD +     Ns)] = make_float2(t1.x - t3.y, t1.y + t3.x);
    dst[SW(idxD + 2 * Ns)] = make_float2(t0.x - t2.x, t0.y - t2.y);
    dst[SW(idxD + 3 * Ns)] = make_float2(t1.x + t3.y, t1.y - t3.x);
}

// Hermitian pack + Stockham stage 0 fused (registers -> dst[4j+q]).
__device__ __forceinline__ void pack_st0(float2* __restrict__ dst, int j,
                                         const float2* tw_pack,
                                         const float* car, const float* cai,
                                         const float* cbr, const float* cbi) {
    float2 z[4];
    #pragma unroll
    for (int kk = 0; kk < 4; ++kk) {
        float arv = car[kk], aiv = cai[kk];
        float brv = cbr[kk], biv = cbi[kk];
        if (kk == 0 && j == 0) { aiv = 0.f; biv = 0.f; }  // DC/Nyquist imag ignored
        float Er = 0.5f * (arv + brv), Ei = 0.5f * (aiv - biv);
        float Dr = 0.5f * (arv - brv), Di = 0.5f * (aiv + biv);
        float2 t = tw_pack[kk];
        float Or = Dr * t.x - Di * t.y;
        float Oi = Dr * t.y + Di * t.x;
        z[kk] = make_float2(Er - Oi, Ei + Or);
    }
    float2 t0 = make_float2(z[0].x + z[2].x, z[0].y + z[2].y);
    float2 t1 = make_float2(z[0].x - z[2].x, z[0].y - z[2].y);
    float2 t2 = make_float2(z[1].x + z[3].x, z[1].y + z[3].y);
    float2 t3 = make_float2(z[1].x - z[3].x, z[1].y - z[3].y);
    dst[SW(4*j    )] = make_float2(t0.x + t2.x, t0.y + t2.y);
    dst[SW(4*j + 1)] = make_float2(t1.x - t3.y, t1.y + t3.x);
    dst[SW(4*j + 2)] = make_float2(t0.x - t2.x, t0.y - t2.y);
    dst[SW(4*j + 3)] = make_float2(t1.x + t3.y, t1.y - t3.x);
}

// Stage 4 in registers (natural-order output) + windowed accumulate.
__device__ __forceinline__ void st4_ola(const float2* __restrict__ buf,
                                        float2* acc2, int j, int f_rel,
                                        float2 w1, float2 w2, float2 w3,
                                        const float wreg[4][2]) {
    float2 v0 = buf[SW(j)];
    float2 v1 = buf[SW(j + 256)];
    float2 v2 = buf[SW(j + 512)];
    float2 v3 = buf[SW(j + 768)];
    v1 = cmul(v1, w1); v2 = cmul(v2, w2); v3 = cmul(v3, w3);
    float2 t0 = make_float2(v0.x + v2.x, v0.y + v2.y);
    float2 t1 = make_float2(v0.x - v2.x, v0.y - v2.y);
    float2 t2 = make_float2(v1.x + v3.x, v1.y + v3.y);
    float2 t3 = make_float2(v1.x - v3.x, v1.y - v3.y);
    float2 g[4];
    g[0] = make_float2(t0.x + t2.x, t0.y + t2.y);   // n = j
    g[1] = make_float2(t1.x - t3.y, t1.y + t3.x);   // n = j+256
    g[2] = make_float2(t0.x - t2.x, t0.y - t2.y);   // n = j+512
    g[3] = make_float2(t1.x + t3.y, t1.y - t3.x);   // n = j+768
    const int ofs2 = 256 * f_rel;                   // float2 offset (may be <0)
    #pragma unroll
    for (int q = 0; q < 4; ++q) {
        int i2 = ofs2 + j + q * 256;
        if ((unsigned)i2 < (unsigned)(ACC_N / 2)) {
            float2 a = acc2[i2];
            a.x += g[q].x * wreg[q][0];
            a.y += g[q].y * wreg[q][1];
            acc2[i2] = a;
        }
    }
}

__device__ __forceinline__ void load_spec(const float* __restrict__ sr,
                                          const float* __restrict__ si,
                                          int b, int f, int j,
                                          float* car, float* cai,
                                          float* cbr, float* cbi) {
    const size_t fb = ((size_t)b * NFRAMES + f) * NB;
    const float* __restrict__ xr = sr + fb;
    const float* __restrict__ xi = si + fb;
    #pragma unroll
    for (int kk = 0; kk < 4; ++kk) {
        int k  = j + kk * 256;
        int mk = M - k;
        car[kk] = xr[k];  cai[kk] = xi[k];
        cbr[kk] = xr[mk]; cbi[kk] = xi[mk];
    }
}

// Region-owned OLA; out-of-place Stockham; TWO independent frames per
// barrier segment (4 barriers / 2 frames, 2x ILP per segment).
__global__ __launch_bounds__(256) void istft_region_kernel(
    const float* __restrict__ sr, const float* __restrict__ si,
    float* __restrict__ out)
{
    __shared__ float2 bA0[M], bA1[M];
    __shared__ float2 bB0[M], bB1[M];
    __shared__ float2 acc2[ACC_N / 2];   // 16 KB accumulator

    const int blk = blockIdx.x;
    const int b   = blk / REG_PB;
    const int reg = blk - b * REG_PB;
    const int s0h = reg * R_HOPS;        // first hop owned (untrimmed units)
    const int j   = threadIdx.x;

    #pragma unroll
    for (int q = 0; q < ACC_N / 2 / 256; ++q)
        acc2[j + q * 256] = make_float2(0.f, 0.f);

    // ---- per-block precompute (reused across all frames) ----
    float2 tw_pack[4];
    #pragma unroll
    for (int kk = 0; kk < 4; ++kk) {
        int k = j + kk * 256;
        float s, c;
        __sincosf(PI_F * (float)k * (1.0f / (float)M), &s, &c);
        tw_pack[kk] = make_float2(c, s);
    }
    float2 w1s[4], w2s[4], w3s[4];       // stages 1..4
    #pragma unroll
    for (int st = 1; st <= 4; ++st) {
        int Ns = 1 << (2 * st);
        int jm = j & (Ns - 1);
        float ang = (0.5f * PI_F / (float)Ns) * (float)jm;
        float s1, c1;
        __sincosf(ang, &s1, &c1);
        float2 w1 = make_float2(c1, s1);
        w1s[st-1] = w1;
        w2s[st-1] = cmul(w1, w1);
        w3s[st-1] = cmul(w2s[st-1], w1);
    }
    float wreg[4][2];                    // hann(t)^2 / M for t = 2n, 2n+1
    #pragma unroll
    for (int q = 0; q < 4; ++q) {
        int n = j + q * 256;
        #pragma unroll
        for (int h = 0; h < 2; ++h) {
            int t = 2 * n + h;
            float swv = __sinf((PI_F / (float)FFTN) * (float)t);
            wreg[q][h] = swv * swv * (1.0f / 1024.0f);
        }
    }

    int f0 = s0h - 3;           if (f0 < 0)           f0 = 0;
    int f1 = s0h + R_HOPS - 1;  if (f1 > NFRAMES - 1) f1 = NFRAMES - 1;

    __syncthreads();   // acc zeroed

    for (int f = f0; f <= f1; f += 2) {
        const bool haveB = (f + 1 <= f1);

        // ---- load both frames' spectra (loads issue together; B's pack
        //      compute covers A's load latency) ----
        float arA[4], aiA[4], brA[4], biA[4];
        float arB[4], aiB[4], brB[4], biB[4];
        load_spec(sr, si, b, f, j, arA, aiA, brA, biA);
        if (haveB) load_spec(sr, si, b, f + 1, j, arB, aiB, brB, biB);

        pack_st0(bA0, j, tw_pack, arA, aiA, brA, biA);
        if (haveB) pack_st0(bB0, j, tw_pack, arB, aiB, brB, biB);
        __syncthreads();

        stage<1>(bA0, bA1, j, w1s[0], w2s[0], w3s[0]);
        if (haveB) stage<1>(bB0, bB1, j, w1s[0], w2s[0], w3s[0]);
        __syncthreads();

        stage<2>(bA1, bA0, j, w1s[1], w2s[1], w3s[1]);
        if (haveB) stage<2>(bB1, bB0, j, w1s[1], w2s[1], w3s[1]);
        __syncthreads();

        stage<3>(bA0, bA1, j, w1s[2], w2s[2], w3s[2]);
        if (haveB) stage<3>(bB0, bB1, j, w1s[2], w2s[2], w3s[2]);
        __syncthreads();

        st4_ola(bA1, acc2, j, f - s0h, w1s[3], w2s[3], w3s[3], wreg);
        if (haveB) st4_ola(bB1, acc2, j, f + 1 - s0h, w1s[3], w2s[3], w3s[3], wreg);
        // next pack writes bA0/bB0 — disjoint from bA1/bB1 reads: no barrier
    }

    __syncthreads();   // all frames' accumulates done

    // ---- epilogue: divide by window_sumsquare, write once, coalesced ----
    const float* accf = (const float*)acc2;
    const int base_u = s0h * HOP;
    float* outb = out + (size_t)b * OUT_T;
    #pragma unroll
    for (int q = 0; q < ACC_N / 256; ++q) {
        int i = j + q * 256;
        int p = base_u + i - FFTN / 2;
        if ((unsigned)p < (unsigned)OUT_T) {
            float invw = (p < 512 || p >= OUT_T - 512) ? (1.0f / wsq_at(p)) : (2.0f / 3.0f);
            outb[p] = accf[i] * invw;
        }
    }
}

extern "C" void kernel_launch(void* const* d_in, const int* in_sizes, int n_in,
                              void* d_out, int out_size, void* d_ws, size_t ws_size,
                              hipStream_t stream) {
    const float* sr = (const float*)d_in[0];
    const float* si = (const float*)d_in[1];
    float* out = (float*)d_out;
    istft_region_kernel<<<BATCH * REG_PB, 256, 0, stream>>>(sr, si, out);
}

// Round 11
// 73.707 us; speedup vs baseline: 4.4281x; 1.1086x over previous
//
#include <hip/hip_runtime.h>
#include <math.h>

#define NB       1025
#define FFTN     2048
#define HOP      512
#define NFRAMES  4000
#define BATCH    4
#define OUT_T    2047488          // (F-1)*hop + N - 2*half
#define R_HOPS   8
#define REG_PB   501              // ceil(4003/8)
#define ACC_N    (R_HOPS * HOP)   // 4096 floats = 16 KB
#define PI_F     3.14159265358979323846f

__device__ __forceinline__ float2 cmul(float2 a, float2 b) {
    return make_float2(fmaf(a.x, b.x, -a.y*b.y), fmaf(a.x, b.y, a.y*b.x));
}
__device__ __forceinline__ float2 cadd(float2 a, float2 b){ return make_float2(a.x+b.x, a.y+b.y); }
__device__ __forceinline__ float2 csub(float2 a, float2 b){ return make_float2(a.x-b.x, a.y-b.y); }
__device__ __forceinline__ float2 caddi(float2 a, float2 b){ return make_float2(a.x-b.y, a.y+b.x); } // a + i*b
__device__ __forceinline__ float2 csubi(float2 a, float2 b){ return make_float2(a.x+b.y, a.y-b.x); } // a - i*b

template<int CTRL>
__device__ __forceinline__ float dppx(float v) {
    return __int_as_float(__builtin_amdgcn_mov_dpp(__float_as_int(v), CTRL, 0xF, 0xF, true));
}
// ctrl: 0x4E = quad_perm[2,3,0,1] (lane^2); 0xB1 = quad_perm[1,0,3,2] (lane^1)
// 0x124 = row_ror:4, 0x128 = row_ror:8 (lane^8 exact), 0x12C = row_ror:12

// window_sumsquare at trimmed position p (boundary path, <=4 terms)
__device__ __forceinline__ float wsq_at(int p) {
    int u  = p + FFTN / 2;
    int fm = u >> 9;
    int n0 = u & 511;
    float wsq = 0.f;
    #pragma unroll
    for (int jj = 0; jj < 4; ++jj) {
        int fr = fm - jj;
        if (fr >= 0 && fr < NFRAMES) {
            int n = n0 + (jj << 9);
            float sw = __sinf((PI_F / (float)FFTN) * (float)n);
            float w  = sw * sw;
            wsq += w * w;
        }
    }
    const float tiny = 1.17549435e-38f;
    return (wsq > tiny) ? wsq : 1.0f;
}

// inverse radix-4 across the 4-lane quad (verified R8 pattern); lane u ends
// with output index br2(u).
__device__ __forceinline__ float2 qdft4(float2 v, float sX, float sY, bool b1, bool b2) {
    float px = dppx<0x4E>(v.x), py = dppx<0x4E>(v.y);
    float2 B = make_float2(fmaf(sX, v.x, px), fmaf(sX, v.y, py));
    float qx = dppx<0xB1>(B.x), qy = dppx<0xB1>(B.y);
    float2 Q = make_float2(qx, qy);
    float2 m1 = b1 ? Q : B;
    float2 m2 = b1 ? B : Q;
    float2 m2r = b2 ? make_float2(-m2.y, m2.x) : m2;   // * i (inverse)
    return make_float2(fmaf(sY, m2r.x, m1.x), fmaf(sY, m2r.y, m1.y));
}

// inverse radix-4 across lane bits 2-3 (c = (lane>>2)&3) via row_ror DPP;
// partner lane^8 exact; partner lane^4 via probe-resolved ror4/ror12 select.
__device__ __forceinline__ float2 rdft4(float2 v, float sX, float sY, bool b1, bool b2, bool use_r4) {
    float px = dppx<0x128>(v.x), py = dppx<0x128>(v.y);
    float2 B = make_float2(fmaf(sX, v.x, px), fmaf(sX, v.y, py));
    float x4 = dppx<0x124>(B.x), x12 = dppx<0x12C>(B.x);
    float y4 = dppx<0x124>(B.y), y12 = dppx<0x12C>(B.y);
    float2 Q = make_float2(use_r4 ? x4 : x12, use_r4 ? y4 : y12);
    float2 m1 = b1 ? Q : B;
    float2 m2 = b1 ? B : Q;
    float2 m2r = b2 ? make_float2(-m2.y, m2.x) : m2;
    return make_float2(fmaf(sY, m2r.x, m1.x), fmaf(sY, m2r.y, m1.y));
}

__device__ __forceinline__ void load_spec(const float* __restrict__ sr,
                                          const float* __restrict__ si,
                                          int b, int f, int j,
                                          float* car, float* cai,
                                          float* cbr, float* cbi) {
    const size_t fb = ((size_t)b * NFRAMES + f) * NB;
    const float* __restrict__ xr = sr + fb;
    const float* __restrict__ xi = si + fb;
    #pragma unroll
    for (int kk = 0; kk < 4; ++kk) {
        int k  = j + kk * 256;
        int mk = 1024 - k;
        car[kk] = xr[k];  cai[kk] = xi[k];
        cbr[kk] = xr[mk]; cbi[kk] = xi[mk];
    }
}

// Region-owned OLA; 1024 = 4*16*16 decomposition: 2 LDS hops + DPP cross-lane
// radix-4s; 2 barriers/frame; 32KB LDS -> 5 blocks/CU.
__global__ __launch_bounds__(256, 5) void istft_r16_kernel(
    const float* __restrict__ sr, const float* __restrict__ si,
    float* __restrict__ out)
{
    __shared__ float2 bufZ[1024];        // 8 KB: packed spectrum (linear)
    __shared__ float2 bufT[1024];        // 8 KB: after step1 (64*n2 + 4*k1 + k0)
    __shared__ float2 acc2[ACC_N / 2];   // 16 KB accumulator (swizzled)

    const int t    = threadIdx.x;
    const int l    = t & 63;
    const int u    = t & 3;              // quad lane: k2-mod-4 digit / k1-mod-4 digit
    const int c    = (t >> 2) & 3;       // k0 digit (lane bits 2-3)
    const int k1   = t >> 4;             // k1 in step1; n2 in step3
    const int br2u = ((u & 1) << 1) | (u >> 1);
    const int br2c = ((c & 1) << 1) | (c >> 1);
    const int blk  = blockIdx.x;
    const int b    = blk / REG_PB;
    const int reg  = blk - b * REG_PB;
    const int s0h  = reg * R_HOPS;

    #pragma unroll
    for (int q = 0; q < ACC_N / 2 / 256; ++q)
        acc2[t + q * 256] = make_float2(0.f, 0.f);

    // ---- per-thread hoisted constants ----
    float2 tw_pack[4];
    #pragma unroll
    for (int kk = 0; kk < 4; ++kk) {
        float s, cv;
        __sincosf(PI_F * (float)(t + 256 * kk) * (1.0f / 1024.0f), &s, &cv);
        tw_pack[kk] = make_float2(cv, s);
    }
    float2 W1a, W1b, W1c;   // w16^{u}, w16^{2u}, w16^{3u}
    { float s, cv; __sincosf((PI_F / 8.f) * (float)u, &s, &cv);
      W1a = make_float2(cv, s); W1b = cmul(W1a, W1a); W1c = cmul(W1b, W1a); }
    float2 B2;   // w256^{k1}
    { float s, cv; __sincosf((PI_F / 128.f) * (float)k1, &s, &cv); B2 = make_float2(cv, s); }
    float2 C0;   // w256^{4*br2u*k1}
    { float s, cv; __sincosf((PI_F / 32.f) * (float)(br2u * k1), &s, &cv); C0 = make_float2(cv, s); }
    float2 Dstep; // w64^{c}
    { float s, cv; __sincosf((PI_F / 32.f) * (float)c, &s, &cv); Dstep = make_float2(cv, s); }
    float2 D0;   // w1024^{(n2 + 64*br2u)*c}, n2 = k1
    { float s, cv; __sincosf((PI_F / 512.f) * (float)((k1 + 64 * br2u) * c), &s, &cv); D0 = make_float2(cv, s); }

    const int n_base = k1 + 64 * br2u + 256 * br2c;   // n = n_base + 16*alpha
    float win[4][2];
    #pragma unroll
    for (int a = 0; a < 4; ++a) {
        #pragma unroll
        for (int h = 0; h < 2; ++h) {
            int tau = 2 * (n_base + 16 * a) + h;
            float s = __sinf((PI_F / 2048.f) * (float)tau);
            win[a][h] = s * s * (1.f / 1024.f);
        }
    }

    const float sXu = (u & 2) ? -1.f : 1.f, sYu = (u & 1) ? -1.f : 1.f;
    const float sXc = (c & 2) ? -1.f : 1.f, sYc = (c & 1) ? -1.f : 1.f;
    const bool  bu1 = (u & 1) != 0, bu2 = (u & 2) != 0;
    const bool  bc1 = (c & 1) != 0, bc2 = (c & 2) != 0;

    // row_ror direction probe (semantics-proof partner select for lane^4)
    bool use_r4;
    {
        float probe = (float)(l & 15);
        float r4p = dppx<0x124>(probe);
        int first = __builtin_amdgcn_readfirstlane(__float_as_int(r4p));
        bool plus_sem = (first == __float_as_int(4.0f));   // lane0 got lane4 -> +N semantics
        use_r4 = plus_sem ? ((l & 4) == 0) : ((l & 4) != 0);
    }

    int f0 = s0h - 3;           if (f0 < 0)           f0 = 0;
    int f1 = s0h + R_HOPS - 1;  if (f1 > NFRAMES - 1) f1 = NFRAMES - 1;

    __syncthreads();   // acc zeroed

    float car[4], cai[4], cbr[4], cbi[4];
    load_spec(sr, si, b, f0, t, car, cai, cbr, cbi);

    for (int f = f0; f <= f1; ++f) {
        // ---- pack -> bufZ (linear), Hermitian fold (R6-verified math) ----
        #pragma unroll
        for (int kk = 0; kk < 4; ++kk) {
            float arv = car[kk], aiv = cai[kk];
            float brv = cbr[kk], biv = cbi[kk];
            if (kk == 0 && t == 0) { aiv = 0.f; biv = 0.f; }
            float Er = 0.5f * (arv + brv), Ei = 0.5f * (aiv - biv);
            float Dr = 0.5f * (arv - brv), Di = 0.5f * (aiv + biv);
            float Or = fmaf(Dr, tw_pack[kk].x, -Di * tw_pack[kk].y);
            float Oi = fmaf(Dr, tw_pack[kk].y,  Di * tw_pack[kk].x);
            bufZ[t + 256 * kk] = make_float2(Er - Oi, Ei + Or);
        }
        // prefetch next frame's spectra (latency hidden under step1/step3)
        float nar[4], nai[4], nbr[4], nbi[4];
        {
            int fn = (f < f1) ? f + 1 : f1;
            load_spec(sr, si, b, fn, t, nar, nai, nbr, nbi);
        }
        __syncthreads();

        // ---- step1: DFT16 over k2 (=u+4v) + twiddle + write ----
        {
            const int base1 = c + 4 * k1 + 64 * u;
            float2 z0 = bufZ[base1];
            float2 z1 = bufZ[base1 + 256];
            float2 z2 = bufZ[base1 + 512];
            float2 z3 = bufZ[base1 + 768];
            float2 t0 = cadd(z0, z2), t1 = csub(z0, z2);
            float2 t2 = cadd(z1, z3), t3 = csub(z1, z3);
            float2 T0 = cadd(t0, t2);
            float2 T1 = caddi(t1, t3);
            float2 T2 = csub(t0, t2);
            float2 T3 = csubi(t1, t3);
            T1 = cmul(T1, W1a); T2 = cmul(T2, W1b); T3 = cmul(T3, W1c);
            float2 A0 = qdft4(T0, sXu, sYu, bu1, bu2);
            float2 A1 = qdft4(T1, sXu, sYu, bu1, bu2);
            float2 A2 = qdft4(T2, sXu, sYu, bu1, bu2);
            float2 A3 = qdft4(T3, sXu, sYu, bu1, bu2);
            // step2 twiddle: w256^{(alpha + 4*br2u)*k1} = C0 * B2^alpha
            float2 w2t = C0;
            A0 = cmul(A0, w2t);
            w2t = cmul(w2t, B2); A1 = cmul(A1, w2t);
            w2t = cmul(w2t, B2); A2 = cmul(A2, w2t);
            w2t = cmul(w2t, B2); A3 = cmul(A3, w2t);
            const int baseT = 256 * br2u + 4 * k1 + c;   // 64*n2 + 4*k1 + k0, n2 = alpha+4br2u
            bufT[baseT      ] = A0;
            bufT[baseT +  64] = A1;
            bufT[baseT + 128] = A2;
            bufT[baseT + 192] = A3;
        }
        __syncthreads();

        // ---- step3: DFT16 over k1 (=u+4v') + step4 twiddle + radix4 over k0 + OLA ----
        {
            const int base3 = 64 * k1 + 4 * u + c;       // n2 = k1 here
            float2 a0 = bufT[base3];
            float2 a1 = bufT[base3 + 16];
            float2 a2 = bufT[base3 + 32];
            float2 a3 = bufT[base3 + 48];
            float2 t0 = cadd(a0, a2), t1 = csub(a0, a2);
            float2 t2 = cadd(a1, a3), t3 = csub(a1, a3);
            float2 S0 = cadd(t0, t2);
            float2 S1 = caddi(t1, t3);
            float2 S2 = csub(t0, t2);
            float2 S3 = csubi(t1, t3);
            S1 = cmul(S1, W1a); S2 = cmul(S2, W1b); S3 = cmul(S3, W1c);
            float2 B0 = qdft4(S0, sXu, sYu, bu1, bu2);
            float2 B1 = qdft4(S1, sXu, sYu, bu1, bu2);
            float2 B2q = qdft4(S2, sXu, sYu, bu1, bu2);
            float2 B3 = qdft4(S3, sXu, sYu, bu1, bu2);
            // step4 twiddle: w1024^{(n2+16*n1)*k0} = D0 * Dstep^alpha
            float2 w4t = D0;
            B0 = cmul(B0, w4t);
            w4t = cmul(w4t, Dstep); B1 = cmul(B1, w4t);
            w4t = cmul(w4t, Dstep); B2q = cmul(B2q, w4t);
            w4t = cmul(w4t, Dstep); B3 = cmul(B3, w4t);
            // step5: radix-4 over k0 across lane bits 2-3
            float2 G0 = rdft4(B0,  sXc, sYc, bc1, bc2, use_r4);
            float2 G1 = rdft4(B1,  sXc, sYc, bc1, bc2, use_r4);
            float2 G2 = rdft4(B2q, sXc, sYc, bc1, bc2, use_r4);
            float2 G3 = rdft4(B3,  sXc, sYc, bc1, bc2, use_r4);
            // window + accumulate (acc swizzled: i ^ ((i>>4)&15))
            const int frel256 = (f - s0h) * 256;
            float2 G[4] = {G0, G1, G2, G3};
            #pragma unroll
            for (int a = 0; a < 4; ++a) {
                int pos2 = frel256 + n_base + 16 * a;
                if ((unsigned)pos2 < (unsigned)(ACC_N / 2)) {
                    int sa = pos2 ^ ((pos2 >> 4) & 15);
                    float2 av = acc2[sa];
                    av.x += G[a].x * win[a][0];
                    av.y += G[a].y * win[a][1];
                    acc2[sa] = av;
                }
            }
        }
        // rotate prefetched spectra into current
        #pragma unroll
        for (int kk = 0; kk < 4; ++kk) {
            car[kk] = nar[kk]; cai[kk] = nai[kk];
            cbr[kk] = nbr[kk]; cbi[kk] = nbi[kk];
        }
        // no barrier: next pack writes bufZ; its readers (step1 of f) are
        // behind the step1 barrier, and step1(f+1) is behind pack's barrier.
    }

    __syncthreads();   // all accumulates done

    // ---- epilogue: unswizzle, divide by window_sumsquare, write once ----
    const int base_u = s0h * HOP;
    float* outb = out + (size_t)b * OUT_T;
    #pragma unroll
    for (int q = 0; q < ACC_N / 2 / 256; ++q) {
        int i2 = t + q * 256;
        int sa = i2 ^ ((i2 >> 4) & 15);
        float2 v = acc2[sa];
        int p0 = base_u + 2 * i2 - FFTN / 2;
        if ((unsigned)p0 < (unsigned)OUT_T) {
            float invw = (p0 < 512 || p0 >= OUT_T - 512) ? (1.0f / wsq_at(p0)) : (2.0f / 3.0f);
            outb[p0] = v.x * invw;
        }
        int p1 = p0 + 1;
        if ((unsigned)p1 < (unsigned)OUT_T) {
            float invw = (p1 < 512 || p1 >= OUT_T - 512) ? (1.0f / wsq_at(p1)) : (2.0f / 3.0f);
            outb[p1] = v.y * invw;
        }
    }
}

extern "C" void kernel_launch(void* const* d_in, const int* in_sizes, int n_in,
                              void* d_out, int out_size, void* d_ws, size_t ws_size,
                              hipStream_t stream) {
    const float* sr = (const float*)d_in[0];
    const float* si = (const float*)d_in[1];
    float* out = (float*)d_out;
    istft_r16_kernel<<<BATCH * REG_PB, 256, 0, stream>>>(sr, si, out);
}